// Round 1
// baseline (553.813 us; speedup 1.0000x reference)
//
#include <hip/hip_runtime.h>
#include <hip/hip_bf16.h>

#define D 128
#define NEG_SLOPE 0.1f
#define CHUNK 1024  // elements per scan chunk

// ---------------- init ----------------
__global__ void k_init_cnt(int* cnt, int n) {
    int i = blockIdx.x * blockDim.x + threadIdx.x;
    if (i < n) cnt[i] = 0;
}

// ---------------- degree count ----------------
__global__ void k_count(const int* __restrict__ dst, int* __restrict__ cnt, int E) {
    int e = blockIdx.x * blockDim.x + threadIdx.x;
    if (e < E) atomicAdd(&cnt[dst[e]], 1);
}

// ---------------- dinv = rsqrt(deg) ----------------
__global__ void k_dinv(const int* __restrict__ cnt, float* __restrict__ dinv, int n) {
    int i = blockIdx.x * blockDim.x + threadIdx.x;
    if (i < n) dinv[i] = rsqrtf((float)(cnt[i] + 1));  // +1 self loop; always > 0
}

// ---------------- scan pass 1: per-chunk sums ----------------
__global__ __launch_bounds__(256) void k_chunk_sums(const int* __restrict__ cnt, int* __restrict__ chunkSum, int n) {
    int b = blockIdx.x, t = threadIdx.x, lane = t & 63, wave = t >> 6;
    int base = b * CHUNK + t * 4;
    int s = 0;
#pragma unroll
    for (int j = 0; j < 4; j++) { int i = base + j; if (i < n) s += cnt[i]; }
#pragma unroll
    for (int d = 32; d > 0; d >>= 1) s += __shfl_down(s, d, 64);
    __shared__ int wsum[4];
    if (lane == 0) wsum[wave] = s;
    __syncthreads();
    if (t == 0) chunkSum[b] = wsum[0] + wsum[1] + wsum[2] + wsum[3];
}

// ---------------- scan pass 2: exclusive scan of chunk sums (1 block, 256 thr) ----------------
__global__ __launch_bounds__(256) void k_scan_tops(const int* __restrict__ chunkSum, int* __restrict__ chunkBase, int nc) {
    __shared__ int sh[256];
    int t = threadIdx.x;
    int v = (t < nc) ? chunkSum[t] : 0;
    sh[t] = v;
    __syncthreads();
    for (int d = 1; d < 256; d <<= 1) {
        int y = 0;
        if (t >= d) y = sh[t - d];
        __syncthreads();
        sh[t] += y;
        __syncthreads();
    }
    if (t < nc) chunkBase[t] = sh[t] - v;  // exclusive
}

// ---------------- scan pass 3: full exclusive scan; writes offs and cursor ----------------
__global__ __launch_bounds__(256) void k_scan_chunks(const int* __restrict__ cnt, const int* __restrict__ chunkBase,
                                                     int* __restrict__ offs, int* __restrict__ cursor, int n) {
    int b = blockIdx.x, t = threadIdx.x, lane = t & 63, wave = t >> 6;
    int base_i = b * CHUNK + t * 4;
    int v[4];
    int s = 0;
#pragma unroll
    for (int j = 0; j < 4; j++) { int i = base_i + j; v[j] = (i < n) ? cnt[i] : 0; s += v[j]; }
    // wave exclusive scan of per-thread sums
    int inc = s;
    for (int d = 1; d < 64; d <<= 1) {
        int y = __shfl_up(inc, d, 64);
        if (lane >= d) inc += y;
    }
    int texcl = inc - s;
    __shared__ int wsum[4];
    if (lane == 63) wsum[wave] = inc;  // wave total
    __syncthreads();
    int woff = 0;
    for (int w = 0; w < wave; w++) woff += wsum[w];
    int base = chunkBase[b] + woff + texcl;
    int run = 0;
#pragma unroll
    for (int j = 0; j < 4; j++) {
        int i = base_i + j;
        if (i < n) { offs[i] = base + run; cursor[i] = base + run; }
        run += v[j];
    }
}

// ---------------- counting-sort scatter: bucket src ids by dst ----------------
__global__ void k_scatter(const int* __restrict__ src, const int* __restrict__ dst,
                          int* __restrict__ cursor, int* __restrict__ sorted_src, int E) {
    int e = blockIdx.x * blockDim.x + threadIdx.x;
    if (e < E) {
        int d = dst[e];
        int pos = atomicAdd(&cursor[d], 1);
        sorted_src[pos] = src[e];
    }
}

// ---------------- GEMM: h = x @ W  (fp32 vector ALU) ----------------
// block = 256 (4 waves); each wave computes 8 rows x 128 cols (float2/lane).
// W staged in LDS (64 KB); x read via wave-uniform scalar loads.
__global__ __launch_bounds__(256) void k_gemm(const float* __restrict__ x, const float* __restrict__ W,
                                              float* __restrict__ h, int n) {
    __shared__ float Wl[D * D];
    int t = threadIdx.x;
    const float4* W4 = (const float4*)W;
    float4* Wl4 = (float4*)Wl;
#pragma unroll
    for (int j = 0; j < 16; j++) Wl4[t + 256 * j] = W4[t + 256 * j];
    __syncthreads();

    int lane = t & 63, wave = t >> 6;
    int rbase = blockIdx.x * 32 + wave * 8;
    rbase = __builtin_amdgcn_readfirstlane(rbase);
    if (rbase >= n) return;

    float2 acc[8];
#pragma unroll
    for (int r = 0; r < 8; r++) { acc[r].x = 0.f; acc[r].y = 0.f; }

    const float4* x4 = (const float4*)x;
    for (int k4 = 0; k4 < 32; k4++) {
        float4 xv[8];
#pragma unroll
        for (int r = 0; r < 8; r++) xv[r] = x4[(rbase + r) * 32 + k4];  // uniform -> s_load
#pragma unroll
        for (int kk = 0; kk < 4; kk++) {
            int k = k4 * 4 + kk;
            float2 w = *(const float2*)&Wl[k * D + 2 * lane];
#pragma unroll
            for (int r = 0; r < 8; r++) {
                float xs = (kk == 0) ? xv[r].x : (kk == 1) ? xv[r].y : (kk == 2) ? xv[r].z : xv[r].w;
                acc[r].x += xs * w.x;
                acc[r].y += xs * w.y;
            }
        }
    }
#pragma unroll
    for (int r = 0; r < 8; r++) {
        int row = rbase + r;
        if (row < n) ((float2*)h)[row * 64 + lane] = acc[r];
    }
}

// ---------------- aggregation + epilogue ----------------
// one wave per node; float2 per lane covers D=128.
__global__ __launch_bounds__(64) void k_aggregate(const float* __restrict__ h, const float* __restrict__ x,
                                                  const float* __restrict__ dinv, const float* __restrict__ bias,
                                                  const int* __restrict__ offs, const int* __restrict__ cnt,
                                                  const int* __restrict__ sorted_src,
                                                  float* __restrict__ out, int n) {
    int i = blockIdx.x;
    if (i >= n) return;
    int lane = threadIdx.x;
    float di = dinv[i];
    int start = offs[i];
    int m = cnt[i];
    const float2* h2 = (const float2*)h;

    // self loop: h[i] * di^2
    float2 hv = h2[i * 64 + lane];
    float cself = di * di;
    float2 acc;
    acc.x = hv.x * cself;
    acc.y = hv.y * cself;

    for (int j = 0; j < m; j++) {
        int s = sorted_src[start + j];
        float cs = dinv[s] * di;
        float2 hs = h2[s * 64 + lane];
        acc.x += hs.x * cs;
        acc.y += hs.y * cs;
    }

    float2 bb = ((const float2*)bias)[lane];
    acc.x += bb.x;
    acc.y += bb.y;
    acc.x = (acc.x >= 0.f) ? acc.x : NEG_SLOPE * acc.x;
    acc.y = (acc.y >= 0.f) ? acc.y : NEG_SLOPE * acc.y;
    float2 xv = ((const float2*)x)[i * 64 + lane];
    acc.x += xv.x;
    acc.y += xv.y;
    ((float2*)out)[i * 64 + lane] = acc;
}

extern "C" void kernel_launch(void* const* d_in, const int* in_sizes, int n_in,
                              void* d_out, int out_size, void* d_ws, size_t ws_size,
                              hipStream_t stream) {
    const float* x = (const float*)d_in[0];
    const int* edge_index = (const int*)d_in[1];
    const float* W = (const float*)d_in[2];
    const float* bias = (const float*)d_in[3];
    float* out = (float*)d_out;

    int N = in_sizes[0] / D;
    int E = in_sizes[1] / 2;
    const int* src = edge_index;       // edge_index[0]
    const int* dst = edge_index + E;   // edge_index[1]

    // workspace layout (all 16B aligned)
    char* ws = (char*)d_ws;
    size_t off = 0;
    auto alloc = [&](size_t bytes) {
        void* p = ws + off;
        off += (bytes + 15) & ~(size_t)15;
        return p;
    };
    int* cnt = (int*)alloc((size_t)N * 4);
    int* offs = (int*)alloc((size_t)N * 4);
    int* cursor = (int*)alloc((size_t)N * 4);
    float* dinv = (float*)alloc((size_t)N * 4);
    int nChunks = (N + CHUNK - 1) / CHUNK;
    int* chunkSum = (int*)alloc((size_t)nChunks * 4);
    int* chunkBase = (int*)alloc((size_t)nChunks * 4);
    int* sorted_src = (int*)alloc((size_t)E * 4);
    float* h = (float*)alloc((size_t)N * D * 4);

    int nb_n = (N + 255) / 256;
    int nb_e = (E + 255) / 256;

    k_init_cnt<<<nb_n, 256, 0, stream>>>(cnt, N);
    k_count<<<nb_e, 256, 0, stream>>>(dst, cnt, E);
    k_dinv<<<nb_n, 256, 0, stream>>>(cnt, dinv, N);
    k_chunk_sums<<<nChunks, 256, 0, stream>>>(cnt, chunkSum, N);
    k_scan_tops<<<1, 256, 0, stream>>>(chunkSum, chunkBase, nChunks);
    k_scan_chunks<<<nChunks, 256, 0, stream>>>(cnt, chunkBase, offs, cursor, N);
    k_scatter<<<nb_e, 256, 0, stream>>>(src, dst, cursor, sorted_src, E);
    k_gemm<<<(N + 31) / 32, 256, 0, stream>>>(x, W, h, N);
    k_aggregate<<<N, 64, 0, stream>>>(h, x, dinv, bias, offs, cnt, sorted_src, out, N);
}

// Round 2
// 465.596 us; speedup vs baseline: 1.1895x; 1.1895x over previous
//
#include <hip/hip_runtime.h>
#include <hip/hip_bf16.h>

#define D 128
#define NEG_SLOPE 0.1f
#define CHUNK 1024  // elements per scan chunk

typedef __attribute__((ext_vector_type(8))) short bf16x8;
typedef __attribute__((ext_vector_type(4))) float f32x4;

__device__ inline unsigned short f2bf(float f) {
    unsigned u = __builtin_bit_cast(unsigned, f);
    u += 0x7fff + ((u >> 16) & 1);  // round-to-nearest-even
    return (unsigned short)(u >> 16);
}
__device__ inline float bflo2f(unsigned u) { return __builtin_bit_cast(float, u << 16); }
__device__ inline float bfhi2f(unsigned u) { return __builtin_bit_cast(float, u & 0xffff0000u); }

// ---------------- init cnt + transpose W to bf16 Wt[n][k] ----------------
__global__ void k_init_wt(int* __restrict__ cnt, int n, const float* __restrict__ W,
                          unsigned short* __restrict__ Wt) {
    int b = blockIdx.x;
    int nb_n = (n + 255) / 256;
    if (b < nb_n) {
        int i = b * 256 + threadIdx.x;
        if (i < n) cnt[i] = 0;
    } else {
        int t = (b - nb_n) * 256 + threadIdx.x;  // 0..16383
        int k = t >> 7, nn = t & 127;
        Wt[nn * D + k] = f2bf(W[k * D + nn]);
    }
}

// ---------------- degree count ----------------
__global__ void k_count(const int* __restrict__ dst, int* __restrict__ cnt, int E) {
    int e = blockIdx.x * blockDim.x + threadIdx.x;
    if (e < E) atomicAdd(&cnt[dst[e]], 1);
}

// ---------------- scan pass 1: per-chunk sums (+ fused dinv) ----------------
__global__ __launch_bounds__(256) void k_chunk_sums(const int* __restrict__ cnt, int* __restrict__ chunkSum,
                                                    float* __restrict__ dinv, int n) {
    int b = blockIdx.x, t = threadIdx.x, lane = t & 63, wave = t >> 6;
    int base = b * CHUNK + t * 4;
    int s = 0;
#pragma unroll
    for (int j = 0; j < 4; j++) {
        int i = base + j;
        if (i < n) {
            int c = cnt[i];
            s += c;
            dinv[i] = rsqrtf((float)(c + 1));  // +1 self loop
        }
    }
#pragma unroll
    for (int d = 32; d > 0; d >>= 1) s += __shfl_down(s, d, 64);
    __shared__ int wsum[4];
    if (lane == 0) wsum[wave] = s;
    __syncthreads();
    if (t == 0) chunkSum[b] = wsum[0] + wsum[1] + wsum[2] + wsum[3];
}

// ---------------- scan pass 2: exclusive scan of chunk sums (1 block) ----------------
__global__ __launch_bounds__(256) void k_scan_tops(const int* __restrict__ chunkSum, int* __restrict__ chunkBase, int nc) {
    __shared__ int sh[256];
    int t = threadIdx.x;
    int v = (t < nc) ? chunkSum[t] : 0;
    sh[t] = v;
    __syncthreads();
    for (int d = 1; d < 256; d <<= 1) {
        int y = 0;
        if (t >= d) y = sh[t - d];
        __syncthreads();
        sh[t] += y;
        __syncthreads();
    }
    if (t < nc) chunkBase[t] = sh[t] - v;  // exclusive
}

// ---------------- scan pass 3: full exclusive scan; writes offs and cursor ----------------
__global__ __launch_bounds__(256) void k_scan_chunks(const int* __restrict__ cnt, const int* __restrict__ chunkBase,
                                                     int* __restrict__ offs, int* __restrict__ cursor, int n) {
    int b = blockIdx.x, t = threadIdx.x, lane = t & 63, wave = t >> 6;
    int base_i = b * CHUNK + t * 4;
    int v[4];
    int s = 0;
#pragma unroll
    for (int j = 0; j < 4; j++) { int i = base_i + j; v[j] = (i < n) ? cnt[i] : 0; s += v[j]; }
    int inc = s;
    for (int d = 1; d < 64; d <<= 1) {
        int y = __shfl_up(inc, d, 64);
        if (lane >= d) inc += y;
    }
    int texcl = inc - s;
    __shared__ int wsum[4];
    if (lane == 63) wsum[wave] = inc;
    __syncthreads();
    int woff = 0;
    for (int w = 0; w < wave; w++) woff += wsum[w];
    int base = chunkBase[b] + woff + texcl;
    int run = 0;
#pragma unroll
    for (int j = 0; j < 4; j++) {
        int i = base_i + j;
        if (i < n) { offs[i] = base + run; cursor[i] = base + run; }
        run += v[j];
    }
}

// ---------------- counting-sort scatter: bucket src ids by dst ----------------
__global__ void k_scatter(const int* __restrict__ src, const int* __restrict__ dst,
                          int* __restrict__ cursor, int* __restrict__ sorted_src, int E) {
    int e = blockIdx.x * blockDim.x + threadIdx.x;
    if (e < E) {
        int d = dst[e];
        int pos = atomicAdd(&cursor[d], 1);
        sorted_src[pos] = src[e];
    }
}

// ---------------- MFMA GEMM: h(bf16) = x(fp32->bf16) @ W ----------------
// block = 256 (4 waves). Tile: 128 rows x 128 cols. Wt (bf16, [n][k]) staged
// in LDS padded to 136/row (conflict-free at 8-dword/bank floor). A fragments
// loaded directly from global x (fp32) + converted. 64 MFMAs/wave.
__global__ __launch_bounds__(256) void k_gemm(const float* __restrict__ x,
                                              const unsigned short* __restrict__ Wt,
                                              unsigned short* __restrict__ h, int n) {
    __shared__ unsigned short Wl[D * 136];
    int t = threadIdx.x;
    // stage Wt: 2048 uint4 chunks, 8 per thread; coalesced global read
    const uint4* Wg4 = (const uint4*)Wt;
#pragma unroll
    for (int j = 0; j < 8; j++) {
        int c = t + 256 * j;
        int row = c >> 4, kg = c & 15;
        *(uint4*)&Wl[row * 136 + kg * 8] = Wg4[row * 16 + kg];
    }
    __syncthreads();

    int lane = t & 63, wave = t >> 6;
    int quad = lane >> 4, mrow = lane & 15;
    int rbase = blockIdx.x * 128 + wave * 32;

    // --- load A: 2 row-tiles x 4 k-steps, 8 fp32 each (2 float4) ---
    const float4* x4 = (const float4*)x;
    float4 a0[2][4], a1[2][4];
#pragma unroll
    for (int rt = 0; rt < 2; rt++) {
        int row = rbase + rt * 16 + mrow;
        long rowl = (row < n) ? row : (n - 1);
#pragma unroll
        for (int ks = 0; ks < 4; ks++) {
            long base = rowl * 32 + ks * 8 + quad * 2;  // float4 units (row = 32 float4)
            a0[rt][ks] = x4[base];
            a1[rt][ks] = x4[base + 1];
        }
    }
    // convert to bf16 fragments
    bf16x8 af[2][4];
#pragma unroll
    for (int rt = 0; rt < 2; rt++)
#pragma unroll
        for (int ks = 0; ks < 4; ks++) {
            bf16x8 f;
            f[0] = (short)f2bf(a0[rt][ks].x); f[1] = (short)f2bf(a0[rt][ks].y);
            f[2] = (short)f2bf(a0[rt][ks].z); f[3] = (short)f2bf(a0[rt][ks].w);
            f[4] = (short)f2bf(a1[rt][ks].x); f[5] = (short)f2bf(a1[rt][ks].y);
            f[6] = (short)f2bf(a1[rt][ks].z); f[7] = (short)f2bf(a1[rt][ks].w);
            af[rt][ks] = f;
        }

    f32x4 acc[2][8];
#pragma unroll
    for (int rt = 0; rt < 2; rt++)
#pragma unroll
        for (int ct = 0; ct < 8; ct++) acc[rt][ct] = (f32x4){0.f, 0.f, 0.f, 0.f};

#pragma unroll
    for (int ks = 0; ks < 4; ks++) {
#pragma unroll
        for (int ct = 0; ct < 8; ct++) {
            bf16x8 bf = *(bf16x8*)&Wl[(ct * 16 + mrow) * 136 + ks * 32 + quad * 8];
#pragma unroll
            for (int rt = 0; rt < 2; rt++)
                acc[rt][ct] = __builtin_amdgcn_mfma_f32_16x16x32_bf16(af[rt][ks], bf, acc[rt][ct], 0, 0, 0);
        }
    }

    // store C: row = quad*4 + reg (within tile), col = mrow
#pragma unroll
    for (int rt = 0; rt < 2; rt++) {
#pragma unroll
        for (int reg = 0; reg < 4; reg++) {
            int row = rbase + rt * 16 + quad * 4 + reg;
            if (row < n) {
#pragma unroll
                for (int ct = 0; ct < 8; ct++)
                    h[(long)row * D + ct * 16 + mrow] = f2bf(acc[rt][ct][reg]);
            }
        }
    }
}

// ---------------- aggregation + epilogue (bf16 h gather) ----------------
// 4 nodes per 256-thr block; one wave per node; uint (2xbf16) per lane.
__global__ __launch_bounds__(256) void k_aggregate(const unsigned* __restrict__ h2, const float* __restrict__ x,
                                                   const float* __restrict__ dinv, const float* __restrict__ bias,
                                                   const int* __restrict__ offs, const int* __restrict__ cnt,
                                                   const int* __restrict__ sorted_src,
                                                   float* __restrict__ out, int n) {
    int wave = threadIdx.x >> 6, lane = threadIdx.x & 63;
    int i = blockIdx.x * 4 + wave;
    if (i >= n) return;
    float di = dinv[i];
    int start = offs[i];
    int m = cnt[i];

    // self loop: h[i] * di^2
    unsigned hv = h2[(long)i * 64 + lane];
    float cself = di * di;
    float accx = bflo2f(hv) * cself;
    float accy = bfhi2f(hv) * cself;

    for (int j = 0; j < m; j++) {
        int s = sorted_src[start + j];
        float cs = dinv[s] * di;
        unsigned hu = h2[(long)s * 64 + lane];
        accx += bflo2f(hu) * cs;
        accy += bfhi2f(hu) * cs;
    }

    float2 bb = ((const float2*)bias)[lane];
    accx += bb.x;
    accy += bb.y;
    accx = (accx >= 0.f) ? accx : NEG_SLOPE * accx;
    accy = (accy >= 0.f) ? accy : NEG_SLOPE * accy;
    float2 xv = ((const float2*)x)[(long)i * 64 + lane];
    accx += xv.x;
    accy += xv.y;
    float2 o; o.x = accx; o.y = accy;
    ((float2*)out)[(long)i * 64 + lane] = o;
}

extern "C" void kernel_launch(void* const* d_in, const int* in_sizes, int n_in,
                              void* d_out, int out_size, void* d_ws, size_t ws_size,
                              hipStream_t stream) {
    const float* x = (const float*)d_in[0];
    const int* edge_index = (const int*)d_in[1];
    const float* W = (const float*)d_in[2];
    const float* bias = (const float*)d_in[3];
    float* out = (float*)d_out;

    int N = in_sizes[0] / D;
    int E = in_sizes[1] / 2;
    const int* src = edge_index;       // edge_index[0]
    const int* dst = edge_index + E;   // edge_index[1]

    char* ws = (char*)d_ws;
    size_t off = 0;
    auto alloc = [&](size_t bytes) {
        void* p = ws + off;
        off += (bytes + 15) & ~(size_t)15;
        return p;
    };
    int* cnt = (int*)alloc((size_t)N * 4);
    int* offs = (int*)alloc((size_t)N * 4);
    int* cursor = (int*)alloc((size_t)N * 4);
    float* dinv = (float*)alloc((size_t)N * 4);
    int nChunks = (N + CHUNK - 1) / CHUNK;
    int* chunkSum = (int*)alloc((size_t)nChunks * 4);
    int* chunkBase = (int*)alloc((size_t)nChunks * 4);
    int* sorted_src = (int*)alloc((size_t)E * 4);
    unsigned short* Wt = (unsigned short*)alloc((size_t)D * D * 2);
    unsigned short* h = (unsigned short*)alloc((size_t)N * D * 2);

    int nb_n = (N + 255) / 256;
    int nb_e = (E + 255) / 256;

    k_init_wt<<<nb_n + 64, 256, 0, stream>>>(cnt, N, W, Wt);
    k_count<<<nb_e, 256, 0, stream>>>(dst, cnt, E);
    k_chunk_sums<<<nChunks, 256, 0, stream>>>(cnt, chunkSum, dinv, N);
    k_scan_tops<<<1, 256, 0, stream>>>(chunkSum, chunkBase, nChunks);
    k_scan_chunks<<<nChunks, 256, 0, stream>>>(cnt, chunkBase, offs, cursor, N);
    k_scatter<<<nb_e, 256, 0, stream>>>(src, dst, cursor, sorted_src, E);
    k_gemm<<<(N + 127) / 128, 256, 0, stream>>>(x, Wt, h, N);
    k_aggregate<<<(N + 3) / 4, 256, 0, stream>>>((const unsigned*)h, x, dinv, bias, offs, cnt, sorted_src, out, N);
}

// Round 3
// 392.872 us; speedup vs baseline: 1.4097x; 1.1851x over previous
//
#include <hip/hip_runtime.h>
#include <hip/hip_bf16.h>

#define D 128
#define NEG_SLOPE 0.1f
#define CHUNK 1024  // elements per scan chunk

typedef __attribute__((ext_vector_type(8))) short bf16x8;
typedef __attribute__((ext_vector_type(4))) float f32x4;

__device__ inline unsigned short f2bf(float f) {
    unsigned u = __builtin_bit_cast(unsigned, f);
    u += 0x7fff + ((u >> 16) & 1);  // round-to-nearest-even
    return (unsigned short)(u >> 16);
}
__device__ inline float bflo2f(unsigned u) { return __builtin_bit_cast(float, u << 16); }
__device__ inline float bfhi2f(unsigned u) { return __builtin_bit_cast(float, u & 0xffff0000u); }

// ---------------- init cnt + transpose W to bf16 Wt[n][k] ----------------
__global__ void k_init_wt(int* __restrict__ cnt, int n, const float* __restrict__ W,
                          unsigned short* __restrict__ Wt) {
    int b = blockIdx.x;
    int nb_n = (n + 255) / 256;
    if (b < nb_n) {
        int i = b * 256 + threadIdx.x;
        if (i < n) cnt[i] = 0;
    } else {
        int t = (b - nb_n) * 256 + threadIdx.x;  // 0..16383
        int k = t >> 7, nn = t & 127;
        Wt[nn * D + k] = f2bf(W[k * D + nn]);
    }
}

// ---------------- degree count (4 edges/thread) ----------------
__global__ void k_count(const int* __restrict__ dst, int* __restrict__ cnt, int E) {
    int t = blockIdx.x * blockDim.x + threadIdx.x;
    int base = t * 4;
    if (base + 4 <= E) {
        int4 d = *(const int4*)&dst[base];
        atomicAdd(&cnt[d.x], 1);
        atomicAdd(&cnt[d.y], 1);
        atomicAdd(&cnt[d.z], 1);
        atomicAdd(&cnt[d.w], 1);
    } else {
        for (int e = base; e < E; e++) atomicAdd(&cnt[dst[e]], 1);
    }
}

// ---------------- scan pass 1: per-chunk sums (+ fused dinv) ----------------
__global__ __launch_bounds__(256) void k_chunk_sums(const int* __restrict__ cnt, int* __restrict__ chunkSum,
                                                    float* __restrict__ dinv, int n) {
    int b = blockIdx.x, t = threadIdx.x, lane = t & 63, wave = t >> 6;
    int base = b * CHUNK + t * 4;
    int s = 0;
#pragma unroll
    for (int j = 0; j < 4; j++) {
        int i = base + j;
        if (i < n) {
            int c = cnt[i];
            s += c;
            dinv[i] = rsqrtf((float)(c + 1));  // +1 self loop
        }
    }
#pragma unroll
    for (int d = 32; d > 0; d >>= 1) s += __shfl_down(s, d, 64);
    __shared__ int wsum[4];
    if (lane == 0) wsum[wave] = s;
    __syncthreads();
    if (t == 0) chunkSum[b] = wsum[0] + wsum[1] + wsum[2] + wsum[3];
}

// ---------------- scan pass 2: exclusive scan of chunk sums (1 block) ----------------
__global__ __launch_bounds__(256) void k_scan_tops(const int* __restrict__ chunkSum, int* __restrict__ chunkBase, int nc) {
    __shared__ int sh[256];
    int t = threadIdx.x;
    int v = (t < nc) ? chunkSum[t] : 0;
    sh[t] = v;
    __syncthreads();
    for (int d = 1; d < 256; d <<= 1) {
        int y = 0;
        if (t >= d) y = sh[t - d];
        __syncthreads();
        sh[t] += y;
        __syncthreads();
    }
    if (t < nc) chunkBase[t] = sh[t] - v;  // exclusive
}

// ---------------- scan pass 3: full exclusive scan; writes offs and cursor ----------------
__global__ __launch_bounds__(256) void k_scan_chunks(const int* __restrict__ cnt, const int* __restrict__ chunkBase,
                                                     int* __restrict__ offs, int* __restrict__ cursor, int n) {
    int b = blockIdx.x, t = threadIdx.x, lane = t & 63, wave = t >> 6;
    int base_i = b * CHUNK + t * 4;
    int v[4];
    int s = 0;
#pragma unroll
    for (int j = 0; j < 4; j++) { int i = base_i + j; v[j] = (i < n) ? cnt[i] : 0; s += v[j]; }
    int inc = s;
    for (int d = 1; d < 64; d <<= 1) {
        int y = __shfl_up(inc, d, 64);
        if (lane >= d) inc += y;
    }
    int texcl = inc - s;
    __shared__ int wsum[4];
    if (lane == 63) wsum[wave] = inc;
    __syncthreads();
    int woff = 0;
    for (int w = 0; w < wave; w++) woff += wsum[w];
    int base = chunkBase[b] + woff + texcl;
    int run = 0;
#pragma unroll
    for (int j = 0; j < 4; j++) {
        int i = base_i + j;
        if (i < n) { offs[i] = base + run; cursor[i] = base + run; }
        run += v[j];
    }
}

// ---------------- counting-sort scatter (4 edges/thread) ----------------
__global__ void k_scatter(const int* __restrict__ src, const int* __restrict__ dst,
                          int* __restrict__ cursor, int* __restrict__ sorted_src, int E) {
    int t = blockIdx.x * blockDim.x + threadIdx.x;
    int base = t * 4;
    if (base + 4 <= E) {
        int4 s = *(const int4*)&src[base];
        int4 d = *(const int4*)&dst[base];
        sorted_src[atomicAdd(&cursor[d.x], 1)] = s.x;
        sorted_src[atomicAdd(&cursor[d.y], 1)] = s.y;
        sorted_src[atomicAdd(&cursor[d.z], 1)] = s.z;
        sorted_src[atomicAdd(&cursor[d.w], 1)] = s.w;
    } else {
        for (int e = base; e < E; e++) {
            int pos = atomicAdd(&cursor[dst[e]], 1);
            sorted_src[pos] = src[e];
        }
    }
}

// ---------------- MFMA GEMM: h'(bf16) = (x @ W) * dinv[row] ----------------
// block = 256 (4 waves). Tile: 128 rows x 128 cols. Wt (bf16, [n][k]) staged
// in LDS padded to 136/row. A fragments loaded directly from global x + cvt.
__global__ __launch_bounds__(256) void k_gemm(const float* __restrict__ x,
                                              const unsigned short* __restrict__ Wt,
                                              const float* __restrict__ dinv,
                                              unsigned short* __restrict__ h, int n) {
    __shared__ unsigned short Wl[D * 136];
    int t = threadIdx.x;
    const uint4* Wg4 = (const uint4*)Wt;
#pragma unroll
    for (int j = 0; j < 8; j++) {
        int c = t + 256 * j;
        int row = c >> 4, kg = c & 15;
        *(uint4*)&Wl[row * 136 + kg * 8] = Wg4[row * 16 + kg];
    }
    __syncthreads();

    int lane = t & 63, wave = t >> 6;
    int quad = lane >> 4, mrow = lane & 15;
    int rbase = blockIdx.x * 128 + wave * 32;

    const float4* x4 = (const float4*)x;
    float4 a0[2][4], a1[2][4];
#pragma unroll
    for (int rt = 0; rt < 2; rt++) {
        int row = rbase + rt * 16 + mrow;
        long rowl = (row < n) ? row : (n - 1);
#pragma unroll
        for (int ks = 0; ks < 4; ks++) {
            long base = rowl * 32 + ks * 8 + quad * 2;
            a0[rt][ks] = x4[base];
            a1[rt][ks] = x4[base + 1];
        }
    }
    bf16x8 af[2][4];
#pragma unroll
    for (int rt = 0; rt < 2; rt++)
#pragma unroll
        for (int ks = 0; ks < 4; ks++) {
            bf16x8 f;
            f[0] = (short)f2bf(a0[rt][ks].x); f[1] = (short)f2bf(a0[rt][ks].y);
            f[2] = (short)f2bf(a0[rt][ks].z); f[3] = (short)f2bf(a0[rt][ks].w);
            f[4] = (short)f2bf(a1[rt][ks].x); f[5] = (short)f2bf(a1[rt][ks].y);
            f[6] = (short)f2bf(a1[rt][ks].z); f[7] = (short)f2bf(a1[rt][ks].w);
            af[rt][ks] = f;
        }

    f32x4 acc[2][8];
#pragma unroll
    for (int rt = 0; rt < 2; rt++)
#pragma unroll
        for (int ct = 0; ct < 8; ct++) acc[rt][ct] = (f32x4){0.f, 0.f, 0.f, 0.f};

#pragma unroll
    for (int ks = 0; ks < 4; ks++) {
#pragma unroll
        for (int ct = 0; ct < 8; ct++) {
            bf16x8 bf = *(bf16x8*)&Wl[(ct * 16 + mrow) * 136 + ks * 32 + quad * 8];
#pragma unroll
            for (int rt = 0; rt < 2; rt++)
                acc[rt][ct] = __builtin_amdgcn_mfma_f32_16x16x32_bf16(af[rt][ks], bf, acc[rt][ct], 0, 0, 0);
        }
    }

    // store h' = acc * dinv[row]; C layout: row = quad*4+reg, col = ct*16+mrow
#pragma unroll
    for (int rt = 0; rt < 2; rt++) {
#pragma unroll
        for (int reg = 0; reg < 4; reg++) {
            int row = rbase + rt * 16 + quad * 4 + reg;
            if (row < n) {
                float dv = dinv[row];
#pragma unroll
                for (int ct = 0; ct < 8; ct++)
                    h[(long)row * D + ct * 16 + mrow] = f2bf(acc[rt][ct][reg] * dv);
            }
        }
    }
}

// ---------------- aggregation + epilogue (4-slot MLP gather) ----------------
// 4 nodes per 256-thr block; one wave per node.
// lane = slot(0..3) * 16 + chunk(0..15); slot group gathers a full 256 B
// h'-row per instruction (uint4/lane); 8 edges in flight per wave.
__global__ __launch_bounds__(256) void k_aggregate(const uint4* __restrict__ h4, const float* __restrict__ x,
                                                   const float* __restrict__ dinv, const float* __restrict__ bias,
                                                   const int* __restrict__ offs, const int* __restrict__ cnt,
                                                   const int* __restrict__ sorted_src,
                                                   float* __restrict__ out, int n) {
    int wave = threadIdx.x >> 6, lane = threadIdx.x & 63;
    int i = blockIdx.x * 4 + wave;
    if (i >= n) return;
    int slot = lane >> 4, chunk = lane & 15;
    int start = offs[i], m = cnt[i];

    float acc[8];
    if (slot == 0) {  // self loop: h'[i] (sum gets scaled by dinv[i] at the end)
        uint4 v = h4[(long)i * 16 + chunk];
        acc[0] = bflo2f(v.x); acc[1] = bfhi2f(v.x);
        acc[2] = bflo2f(v.y); acc[3] = bfhi2f(v.y);
        acc[4] = bflo2f(v.z); acc[5] = bfhi2f(v.z);
        acc[6] = bflo2f(v.w); acc[7] = bfhi2f(v.w);
    } else {
#pragma unroll
        for (int r = 0; r < 8; r++) acc[r] = 0.f;
    }

    int j0 = 0;
    for (; j0 + 8 <= m; j0 += 8) {
        int ja = start + j0 + slot * 2;
        int s0 = sorted_src[ja];
        int s1 = sorted_src[ja + 1];
        uint4 v0 = h4[(long)s0 * 16 + chunk];
        uint4 v1 = h4[(long)s1 * 16 + chunk];
        acc[0] += bflo2f(v0.x); acc[1] += bfhi2f(v0.x);
        acc[2] += bflo2f(v0.y); acc[3] += bfhi2f(v0.y);
        acc[4] += bflo2f(v0.z); acc[5] += bfhi2f(v0.z);
        acc[6] += bflo2f(v0.w); acc[7] += bfhi2f(v0.w);
        acc[0] += bflo2f(v1.x); acc[1] += bfhi2f(v1.x);
        acc[2] += bflo2f(v1.y); acc[3] += bfhi2f(v1.y);
        acc[4] += bflo2f(v1.z); acc[5] += bfhi2f(v1.z);
        acc[6] += bflo2f(v1.w); acc[7] += bfhi2f(v1.w);
    }
    for (int j = j0 + slot; j < m; j += 4) {
        int s = sorted_src[start + j];
        uint4 v = h4[(long)s * 16 + chunk];
        acc[0] += bflo2f(v.x); acc[1] += bfhi2f(v.x);
        acc[2] += bflo2f(v.y); acc[3] += bfhi2f(v.y);
        acc[4] += bflo2f(v.z); acc[5] += bfhi2f(v.z);
        acc[6] += bflo2f(v.w); acc[7] += bfhi2f(v.w);
    }

    // sum the 4 slots (chunk preserved)
#pragma unroll
    for (int r = 0; r < 8; r++) {
        acc[r] += __shfl_xor(acc[r], 16, 64);
        acc[r] += __shfl_xor(acc[r], 32, 64);
    }

    // epilogue: slot writes dims chunk*8 + slot*2 + {0,1}
    float di = dinv[i];
    int dbase = chunk * 8 + slot * 2;
    float2 bb = *(const float2*)&bias[dbase];
    float2 xv = *(const float2*)&x[(long)i * D + dbase];
    float ax = acc[slot * 2] * di + bb.x;
    float ay = acc[slot * 2 + 1] * di + bb.y;
    ax = (ax >= 0.f) ? ax : NEG_SLOPE * ax;
    ay = (ay >= 0.f) ? ay : NEG_SLOPE * ay;
    float2 o;
    o.x = ax + xv.x;
    o.y = ay + xv.y;
    *(float2*)&out[(long)i * D + dbase] = o;
}

extern "C" void kernel_launch(void* const* d_in, const int* in_sizes, int n_in,
                              void* d_out, int out_size, void* d_ws, size_t ws_size,
                              hipStream_t stream) {
    const float* x = (const float*)d_in[0];
    const int* edge_index = (const int*)d_in[1];
    const float* W = (const float*)d_in[2];
    const float* bias = (const float*)d_in[3];
    float* out = (float*)d_out;

    int N = in_sizes[0] / D;
    int E = in_sizes[1] / 2;
    const int* src = edge_index;       // edge_index[0]
    const int* dst = edge_index + E;   // edge_index[1]

    char* ws = (char*)d_ws;
    size_t off = 0;
    auto alloc = [&](size_t bytes) {
        void* p = ws + off;
        off += (bytes + 15) & ~(size_t)15;
        return p;
    };
    int* cnt = (int*)alloc((size_t)N * 4);
    int* offs = (int*)alloc((size_t)N * 4);
    int* cursor = (int*)alloc((size_t)N * 4);
    float* dinv = (float*)alloc((size_t)N * 4);
    int nChunks = (N + CHUNK - 1) / CHUNK;
    int* chunkSum = (int*)alloc((size_t)nChunks * 4);
    int* chunkBase = (int*)alloc((size_t)nChunks * 4);
    int* sorted_src = (int*)alloc((size_t)E * 4);
    unsigned short* Wt = (unsigned short*)alloc((size_t)D * D * 2);
    unsigned short* h = (unsigned short*)alloc((size_t)N * D * 2);

    int nb_n = (N + 255) / 256;
    int nb_e4 = (E / 4 + 255) / 256 + 1;

    k_init_wt<<<nb_n + 64, 256, 0, stream>>>(cnt, N, W, Wt);
    k_count<<<nb_e4, 256, 0, stream>>>(dst, cnt, E);
    k_chunk_sums<<<nChunks, 256, 0, stream>>>(cnt, chunkSum, dinv, N);
    k_scan_tops<<<1, 256, 0, stream>>>(chunkSum, chunkBase, nChunks);
    k_scan_chunks<<<nChunks, 256, 0, stream>>>(cnt, chunkBase, offs, cursor, N);
    k_scatter<<<nb_e4, 256, 0, stream>>>(src, dst, cursor, sorted_src, E);
    k_gemm<<<(N + 127) / 128, 256, 0, stream>>>(x, Wt, dinv, h, N);
    k_aggregate<<<(N + 3) / 4, 256, 0, stream>>>((const uint4*)h, x, dinv, bias, offs, cnt, sorted_src, out, N);
}

// Round 4
// 262.097 us; speedup vs baseline: 2.1130x; 1.4990x over previous
//
#include <hip/hip_runtime.h>
#include <hip/hip_bf16.h>

#define D 128
#define NEG_SLOPE 0.1f
// bucket sort: 512 nodes per bucket; pack = (dstLocal<<17)|src  (valid: N < 2^17)
#define BSHIFT 9
#define BSIZE 512
#define SRCBITS 17
#define SRCMASK 0x1FFFF

typedef __attribute__((ext_vector_type(8))) short bf16x8;
typedef __attribute__((ext_vector_type(4))) float f32x4;

__device__ inline unsigned short f2bf(float f) {
    unsigned u = __builtin_bit_cast(unsigned, f);
    u += 0x7fff + ((u >> 16) & 1);  // round-to-nearest-even
    return (unsigned short)(u >> 16);
}
__device__ inline float bflo2f(unsigned u) { return __builtin_bit_cast(float, u << 16); }
__device__ inline float bfhi2f(unsigned u) { return __builtin_bit_cast(float, u & 0xffff0000u); }

// ---------------- transpose W to bf16 Wt[n][k] + zero bucketCnt ----------------
__global__ void k_init_wt(const float* __restrict__ W, unsigned short* __restrict__ Wt,
                          int* __restrict__ bucketCnt, int NB) {
    int b = blockIdx.x;
    if (b < 64) {
        int t = b * 256 + threadIdx.x;  // 0..16383
        int k = t >> 7, nn = t & 127;
        Wt[nn * D + k] = f2bf(W[k * D + nn]);
    } else {
        if ((int)threadIdx.x < NB) bucketCnt[threadIdx.x] = 0;
    }
}

// ---------------- bucket histogram (LDS-aggregated) ----------------
__global__ __launch_bounds__(256) void k_bucket_count(const int* __restrict__ dst,
                                                      int* __restrict__ bucketCnt, int E, int NB) {
    __shared__ int hist[256];
    int t = threadIdx.x;
    hist[t] = 0;
    __syncthreads();
    const int4* dst4 = (const int4*)dst;
#pragma unroll
    for (int j = 0; j < 4; j++) {
        int i4 = blockIdx.x * 1024 + j * 256 + t;
        int e = i4 * 4;
        if (e + 4 <= E) {
            int4 d = dst4[i4];
            atomicAdd(&hist[d.x >> BSHIFT], 1);
            atomicAdd(&hist[d.y >> BSHIFT], 1);
            atomicAdd(&hist[d.z >> BSHIFT], 1);
            atomicAdd(&hist[d.w >> BSHIFT], 1);
        } else {
            for (int k = e; k < E; k++) atomicAdd(&hist[dst[k] >> BSHIFT], 1);
        }
    }
    __syncthreads();
    if (t < NB && hist[t]) atomicAdd(&bucketCnt[t], hist[t]);
}

// ---------------- scan bucket counts (1 block); init cursor; sentinels ----------------
__global__ __launch_bounds__(256) void k_bucket_scan(const int* __restrict__ bucketCnt,
                                                     int* __restrict__ bucketBase, int* __restrict__ bucketCursor,
                                                     int* __restrict__ offs, int NB, int N, int E) {
    __shared__ int sh[256];
    int t = threadIdx.x;
    int v = (t < NB) ? bucketCnt[t] : 0;
    sh[t] = v;
    __syncthreads();
    for (int d = 1; d < 256; d <<= 1) {
        int y = 0;
        if (t >= d) y = sh[t - d];
        __syncthreads();
        sh[t] += y;
        __syncthreads();
    }
    if (t < NB) {
        int excl = sh[t] - v;
        bucketBase[t] = excl;
        bucketCursor[t] = excl;
    }
    if (t == 0) {
        bucketBase[NB] = E;
        offs[N] = E;  // CSR sentinel
    }
}

// ---------------- bucket scatter: packed edges into bucket regions ----------------
__global__ __launch_bounds__(256) void k_bucket_scatter(const int* __restrict__ src, const int* __restrict__ dst,
                                                        int* __restrict__ bucketCursor,
                                                        int* __restrict__ ebuf, int E, int NB) {
    __shared__ int cntL[256], baseL[256], curL[256];
    int t = threadIdx.x;
    cntL[t] = 0;
    curL[t] = 0;
    __syncthreads();

    const int4* src4 = (const int4*)src;
    const int4* dst4 = (const int4*)dst;
    int sv[16], dv[16];
    int nval[4];
#pragma unroll
    for (int j = 0; j < 4; j++) {
        int i4 = blockIdx.x * 1024 + j * 256 + t;
        int e = i4 * 4;
        if (e + 4 <= E) {
            int4 s = src4[i4];
            int4 d = dst4[i4];
            sv[j * 4] = s.x; sv[j * 4 + 1] = s.y; sv[j * 4 + 2] = s.z; sv[j * 4 + 3] = s.w;
            dv[j * 4] = d.x; dv[j * 4 + 1] = d.y; dv[j * 4 + 2] = d.z; dv[j * 4 + 3] = d.w;
            nval[j] = 4;
        } else {
            int c = 0;
            for (int k = e; k < E; k++, c++) { sv[j * 4 + c] = src[k]; dv[j * 4 + c] = dst[k]; }
            nval[j] = c;
        }
    }
    // phase 1: local histogram
#pragma unroll
    for (int j = 0; j < 4; j++)
        for (int k = 0; k < nval[j]; k++) atomicAdd(&cntL[dv[j * 4 + k] >> BSHIFT], 1);
    __syncthreads();
    // phase 2: one global reservation per touched bucket
    if (t < NB) {
        int c = cntL[t];
        if (c) baseL[t] = atomicAdd(&bucketCursor[t], c);
    }
    __syncthreads();
    // phase 3: write packed edges
#pragma unroll
    for (int j = 0; j < 4; j++)
        for (int k = 0; k < nval[j]; k++) {
            int d = dv[j * 4 + k];
            int b = d >> BSHIFT;
            int slot = atomicAdd(&curL[b], 1);
            ebuf[baseL[b] + slot] = ((d & (BSIZE - 1)) << SRCBITS) | sv[j * 4 + k];
        }
}

// ---------------- per-bucket CSR build: offs, dinv, sorted_src ----------------
__global__ __launch_bounds__(256) void k_bucket_csr(const int* __restrict__ ebuf, const int* __restrict__ bucketBase,
                                                    int* __restrict__ offs, float* __restrict__ dinv,
                                                    int* __restrict__ sorted_src, int N) {
    __shared__ int deg[BSIZE];
    __shared__ int wsum[4];
    int b = blockIdx.x, t = threadIdx.x, lane = t & 63, wave = t >> 6;
    int estart = bucketBase[b], eend = bucketBase[b + 1];
    int nstart = b << BSHIFT;

    deg[t] = 0;
    deg[t + 256] = 0;
    __syncthreads();
    for (int e = estart + t; e < eend; e += 256) atomicAdd(&deg[ebuf[e] >> SRCBITS], 1);
    __syncthreads();

    // exclusive scan of deg[512]; thread t owns elements 2t, 2t+1
    int d0 = deg[2 * t], d1 = deg[2 * t + 1];
    int sum = d0 + d1;
    int inc = sum;
    for (int d = 1; d < 64; d <<= 1) {
        int y = __shfl_up(inc, d, 64);
        if (lane >= d) inc += y;
    }
    int texcl = inc - sum;
    if (lane == 63) wsum[wave] = inc;
    __syncthreads();
    int woff = 0;
    for (int w = 0; w < wave; w++) woff += wsum[w];
    int e0 = woff + texcl;  // exclusive prefix before element 2t

    int i = nstart + 2 * t;
    if (i < N) { offs[i] = estart + e0; dinv[i] = rsqrtf((float)(d0 + 1)); }
    if (i + 1 < N) { offs[i + 1] = estart + e0 + d0; dinv[i + 1] = rsqrtf((float)(d1 + 1)); }
    __syncthreads();
    // reuse deg as cursor (init to exclusive offsets)
    deg[2 * t] = e0;
    deg[2 * t + 1] = e0 + d0;
    __syncthreads();
    for (int e = estart + t; e < eend; e += 256) {
        int v = ebuf[e];
        int pos = atomicAdd(&deg[v >> SRCBITS], 1);
        sorted_src[estart + pos] = v & SRCMASK;
    }
}

// ---------------- MFMA GEMM: h'(bf16) = (x @ W) * dinv[row] ----------------
__global__ __launch_bounds__(256) void k_gemm(const float* __restrict__ x,
                                              const unsigned short* __restrict__ Wt,
                                              const float* __restrict__ dinv,
                                              unsigned short* __restrict__ h, int n) {
    __shared__ unsigned short Wl[D * 136];
    int t = threadIdx.x;
    const uint4* Wg4 = (const uint4*)Wt;
#pragma unroll
    for (int j = 0; j < 8; j++) {
        int c = t + 256 * j;
        int row = c >> 4, kg = c & 15;
        *(uint4*)&Wl[row * 136 + kg * 8] = Wg4[row * 16 + kg];
    }
    __syncthreads();

    int lane = t & 63, wave = t >> 6;
    int quad = lane >> 4, mrow = lane & 15;
    int rbase = blockIdx.x * 128 + wave * 32;

    const float4* x4 = (const float4*)x;
    float4 a0[2][4], a1[2][4];
#pragma unroll
    for (int rt = 0; rt < 2; rt++) {
        int row = rbase + rt * 16 + mrow;
        long rowl = (row < n) ? row : (n - 1);
#pragma unroll
        for (int ks = 0; ks < 4; ks++) {
            long base = rowl * 32 + ks * 8 + quad * 2;
            a0[rt][ks] = x4[base];
            a1[rt][ks] = x4[base + 1];
        }
    }
    bf16x8 af[2][4];
#pragma unroll
    for (int rt = 0; rt < 2; rt++)
#pragma unroll
        for (int ks = 0; ks < 4; ks++) {
            bf16x8 f;
            f[0] = (short)f2bf(a0[rt][ks].x); f[1] = (short)f2bf(a0[rt][ks].y);
            f[2] = (short)f2bf(a0[rt][ks].z); f[3] = (short)f2bf(a0[rt][ks].w);
            f[4] = (short)f2bf(a1[rt][ks].x); f[5] = (short)f2bf(a1[rt][ks].y);
            f[6] = (short)f2bf(a1[rt][ks].z); f[7] = (short)f2bf(a1[rt][ks].w);
            af[rt][ks] = f;
        }

    f32x4 acc[2][8];
#pragma unroll
    for (int rt = 0; rt < 2; rt++)
#pragma unroll
        for (int ct = 0; ct < 8; ct++) acc[rt][ct] = (f32x4){0.f, 0.f, 0.f, 0.f};

#pragma unroll
    for (int ks = 0; ks < 4; ks++) {
#pragma unroll
        for (int ct = 0; ct < 8; ct++) {
            bf16x8 bf = *(bf16x8*)&Wl[(ct * 16 + mrow) * 136 + ks * 32 + quad * 8];
#pragma unroll
            for (int rt = 0; rt < 2; rt++)
                acc[rt][ct] = __builtin_amdgcn_mfma_f32_16x16x32_bf16(af[rt][ks], bf, acc[rt][ct], 0, 0, 0);
        }
    }

#pragma unroll
    for (int rt = 0; rt < 2; rt++) {
#pragma unroll
        for (int reg = 0; reg < 4; reg++) {
            int row = rbase + rt * 16 + quad * 4 + reg;
            if (row < n) {
                float dv = dinv[row];
#pragma unroll
                for (int ct = 0; ct < 8; ct++)
                    h[(long)row * D + ct * 16 + mrow] = f2bf(acc[rt][ct][reg] * dv);
            }
        }
    }
}

// ---------------- aggregation + epilogue (4-slot gather) ----------------
__global__ __launch_bounds__(256) void k_aggregate(const uint4* __restrict__ h4, const float* __restrict__ x,
                                                   const float* __restrict__ dinv, const float* __restrict__ bias,
                                                   const int* __restrict__ offs,
                                                   const int* __restrict__ sorted_src,
                                                   float* __restrict__ out, int n) {
    int wave = threadIdx.x >> 6, lane = threadIdx.x & 63;
    int i = blockIdx.x * 4 + wave;
    if (i >= n) return;
    int slot = lane >> 4, chunk = lane & 15;
    int start = offs[i], m = offs[i + 1] - start;

    float acc[8];
    if (slot == 0) {  // self loop
        uint4 v = h4[(long)i * 16 + chunk];
        acc[0] = bflo2f(v.x); acc[1] = bfhi2f(v.x);
        acc[2] = bflo2f(v.y); acc[3] = bfhi2f(v.y);
        acc[4] = bflo2f(v.z); acc[5] = bfhi2f(v.z);
        acc[6] = bflo2f(v.w); acc[7] = bfhi2f(v.w);
    } else {
#pragma unroll
        for (int r = 0; r < 8; r++) acc[r] = 0.f;
    }

    int j0 = 0;
    for (; j0 + 8 <= m; j0 += 8) {
        int ja = start + j0 + slot * 2;
        int s0 = sorted_src[ja];
        int s1 = sorted_src[ja + 1];
        uint4 v0 = h4[(long)s0 * 16 + chunk];
        uint4 v1 = h4[(long)s1 * 16 + chunk];
        acc[0] += bflo2f(v0.x); acc[1] += bfhi2f(v0.x);
        acc[2] += bflo2f(v0.y); acc[3] += bfhi2f(v0.y);
        acc[4] += bflo2f(v0.z); acc[5] += bfhi2f(v0.z);
        acc[6] += bflo2f(v0.w); acc[7] += bfhi2f(v0.w);
        acc[0] += bflo2f(v1.x); acc[1] += bfhi2f(v1.x);
        acc[2] += bflo2f(v1.y); acc[3] += bfhi2f(v1.y);
        acc[4] += bflo2f(v1.z); acc[5] += bfhi2f(v1.z);
        acc[6] += bflo2f(v1.w); acc[7] += bfhi2f(v1.w);
    }
    for (int j = j0 + slot; j < m; j += 4) {
        int s = sorted_src[start + j];
        uint4 v = h4[(long)s * 16 + chunk];
        acc[0] += bflo2f(v.x); acc[1] += bfhi2f(v.x);
        acc[2] += bflo2f(v.y); acc[3] += bfhi2f(v.y);
        acc[4] += bflo2f(v.z); acc[5] += bfhi2f(v.z);
        acc[6] += bflo2f(v.w); acc[7] += bfhi2f(v.w);
    }

#pragma unroll
    for (int r = 0; r < 8; r++) {
        acc[r] += __shfl_xor(acc[r], 16, 64);
        acc[r] += __shfl_xor(acc[r], 32, 64);
    }

    float di = dinv[i];
    int dbase = chunk * 8 + slot * 2;
    float2 bb = *(const float2*)&bias[dbase];
    float2 xv = *(const float2*)&x[(long)i * D + dbase];
    float ax = acc[slot * 2] * di + bb.x;
    float ay = acc[slot * 2 + 1] * di + bb.y;
    ax = (ax >= 0.f) ? ax : NEG_SLOPE * ax;
    ay = (ay >= 0.f) ? ay : NEG_SLOPE * ay;
    float2 o;
    o.x = ax + xv.x;
    o.y = ay + xv.y;
    *(float2*)&out[(long)i * D + dbase] = o;
}

extern "C" void kernel_launch(void* const* d_in, const int* in_sizes, int n_in,
                              void* d_out, int out_size, void* d_ws, size_t ws_size,
                              hipStream_t stream) {
    const float* x = (const float*)d_in[0];
    const int* edge_index = (const int*)d_in[1];
    const float* W = (const float*)d_in[2];
    const float* bias = (const float*)d_in[3];
    float* out = (float*)d_out;

    int N = in_sizes[0] / D;
    int E = in_sizes[1] / 2;
    const int* src = edge_index;       // edge_index[0]
    const int* dst = edge_index + E;   // edge_index[1]
    int NB = (N + BSIZE - 1) >> BSHIFT;  // buckets (<=256 for N<=131072)

    char* ws = (char*)d_ws;
    size_t off = 0;
    auto alloc = [&](size_t bytes) {
        void* p = ws + off;
        off += (bytes + 15) & ~(size_t)15;
        return p;
    };
    int* offs = (int*)alloc((size_t)(N + 1) * 4);
    float* dinv = (float*)alloc((size_t)N * 4);
    int* bucketCnt = (int*)alloc((size_t)NB * 4);
    int* bucketBase = (int*)alloc((size_t)(NB + 1) * 4);
    int* bucketCursor = (int*)alloc((size_t)NB * 4);
    int* ebuf = (int*)alloc((size_t)E * 4);
    int* sorted_src = (int*)alloc((size_t)E * 4);
    unsigned short* Wt = (unsigned short*)alloc((size_t)D * D * 2);
    unsigned short* h = (unsigned short*)alloc((size_t)N * D * 2);

    int nbE = (E + 4095) / 4096;

    k_init_wt<<<65, 256, 0, stream>>>(W, Wt, bucketCnt, NB);
    k_bucket_count<<<nbE, 256, 0, stream>>>(dst, bucketCnt, E, NB);
    k_bucket_scan<<<1, 256, 0, stream>>>(bucketCnt, bucketBase, bucketCursor, offs, NB, N, E);
    k_bucket_scatter<<<nbE, 256, 0, stream>>>(src, dst, bucketCursor, ebuf, E, NB);
    k_bucket_csr<<<NB, 256, 0, stream>>>(ebuf, bucketBase, offs, dinv, sorted_src, N);
    k_gemm<<<(N + 127) / 128, 256, 0, stream>>>(x, Wt, dinv, h, N);
    k_aggregate<<<(N + 3) / 4, 256, 0, stream>>>((const uint4*)h, x, dinv, bias, offs, sorted_src, out, N);
}